// Round 2
// baseline (166.865 us; speedup 1.0000x reference)
//
#include <hip/hip_runtime.h>

// GDAttention: B=8, S=2048, D=256, H=8.
// out[b,q,d] = (1/(q+1)) * softmax(clip(QK^T/16))·E @ Wsum^T,  Wsum[d][d'] = sum_h W_o[d][h*256+d'].
// Scores are clipped to [-10,10] BEFORE softmax -> no running max needed; partials are additive.

typedef __attribute__((ext_vector_type(8))) short short8;   // 8 x bf16 (4 VGPRs) MFMA frag
typedef __attribute__((ext_vector_type(4))) float f32x4;    // MFMA 16x16 accumulator

__device__ __forceinline__ unsigned short f2b(float x) {    // f32 -> bf16 (round-to-nearest-even)
  unsigned u = __builtin_bit_cast(unsigned, x);
  u = (u + 0x7fffu + ((u >> 16) & 1u)) >> 16;
  return (unsigned short)u;
}

#define GLOAD_LDS16(gp, lp)                                                                        \
  __builtin_amdgcn_global_load_lds((const __attribute__((address_space(1))) unsigned int*)(gp),    \
                                   (__attribute__((address_space(3))) unsigned int*)(lp), 16, 0, 0)

// ---------- pre-pass 1: p (f32 [8][2049][256]) -> bf16, same layout ----------
__global__ void cvt_p_kernel(const float* __restrict__ src, unsigned short* __restrict__ dst) {
  size_t t = (size_t)blockIdx.x * 256 + threadIdx.x;  // 524544 threads, 8 elems each
  const float4* s = (const float4*)(src + t * 8);
  float4 a = s[0], b = s[1];
  short8 o;
  o[0] = (short)f2b(a.x); o[1] = (short)f2b(a.y); o[2] = (short)f2b(a.z); o[3] = (short)f2b(a.w);
  o[4] = (short)f2b(b.x); o[5] = (short)f2b(b.y); o[6] = (short)f2b(b.z); o[7] = (short)f2b(b.w);
  *(short8*)(dst + t * 8) = o;
}

// ---------- pre-pass 2: e (f32 [8][2048][256]) -> B-fragment-ready bf16 ----------
// chunk (b,kt) elem ((d0*64 + lane)*8 + i) = e[b][kt*32 + (lane>>4)*8 + i][d0*16 + (lane&15)]
// => in-kernel E b_frag reads are lane-linear (conflict-free), staging is pure global_load_lds.
__global__ void perm_e_kernel(const float* __restrict__ e, unsigned short* __restrict__ dst) {
  size_t t = (size_t)blockIdx.x * 256 + threadIdx.x;  // 524288 threads
  int lane = (int)(t & 63);
  int d0 = (int)((t >> 6) & 15);
  int kt = (int)((t >> 10) & 63);
  int b = (int)(t >> 16);
  int g = lane >> 4, l = lane & 15;
  const float* s = e + ((size_t)b * 2048 + kt * 32 + g * 8) * 256 + d0 * 16 + l;
  short8 o;
#pragma unroll
  for (int i = 0; i < 8; ++i) o[i] = (short)f2b(s[(size_t)i * 256]);
  *(short8*)(dst + t * 8) = o;
}

// ---------- pre-pass 3: fold W_o over heads, store B-fragment-ready bf16 ----------
__global__ void fold_w_kernel(const float* __restrict__ w, unsigned short* __restrict__ dst) {
  int t = blockIdx.x * 256 + threadIdx.x;  // 8192 threads
  int lane = t & 63;
  int kc = (t >> 6) & 7;
  int d0 = t >> 9;
  int g = lane >> 4, l = lane & 15;
  const float* base = w + (size_t)(d0 * 16 + l) * 2048 + kc * 32 + g * 8;
  short8 o;
#pragma unroll
  for (int i = 0; i < 8; ++i) {
    float sum = 0.f;
#pragma unroll
    for (int h = 0; h < 8; ++h) sum += base[h * 256 + i];
    o[i] = (short)f2b(sum);
  }
  *(short8*)(dst + (size_t)t * 8) = o;
}

// ---------- main kernel ----------
// grid = 256 blocks; decode b = bid&7, pr = bid>>3 so batch b's 32 blocks land on XCD b
// (default round-robin bid%8) -> K/E staging is served by that XCD's 4MB L2
// (per-batch bf16 pool = 1.05MB K + 1.05MB E). [T1 XCD swizzle]
// Block = 4 waves = (qhalf x kvparity); handles q-tiles pr and 63-pr (uniform ~33 k-iters).
// LDS map (bytes):
//   [0,131072)      K/E staging: K(dbuf,par) at dbuf*65536+par*16384 (32x512B rows, XOR-swizzled)
//                   E(dbuf,par) at dbuf*65536+32768+par*16384 (fragment-linear)
//   [131072,136192) P tiles, 1280B/wave ([16][40] bf16)
//   [136192,136320) denom combine [2][16] f32
//   epilogue reuse: YC f32 [2][16][257] at 0 ; PY bf16 [2][16][264] at 65536
#define SMEM_BYTES 136320

__device__ __forceinline__ void stage_tiles(char* smem, int cur, int qh, int par, int kt, int b,
                                            int lane, const unsigned short* pbf,
                                            const unsigned short* eperm) {
  if (qh == 0) {
    // K tile: rows p[b][kt*32 .. +32], 512B each. Dest is linear (HW: base + lane*16);
    // pre-swizzle the SOURCE so reads with byte^=((row&7)<<4) land conflict-free (m173 pattern).
    const char* kb = (const char*)(pbf + ((size_t)b * 2049 + (size_t)kt * 32) * 256);
    char* dst = smem + cur * 65536 + par * 16384;
    int rlo = lane >> 5;
    int ci = (lane & 31) << 4;
#pragma unroll
    for (int j2 = 0; j2 < 16; ++j2) {
      int row = j2 * 2 + rlo;
      GLOAD_LDS16(kb + (row << 9) + (ci ^ ((row & 7) << 4)), dst + j2 * 1024);
    }
  } else {
    const char* eb = (const char*)(eperm + ((size_t)(b * 64 + kt)) * 8192);
    char* dst = smem + cur * 65536 + 32768 + par * 16384;
#pragma unroll
    for (int j2 = 0; j2 < 16; ++j2) GLOAD_LDS16(eb + j2 * 1024 + lane * 16, dst + j2 * 1024);
  }
}

__global__ __launch_bounds__(256, 1) void attn_main_kernel(const unsigned short* __restrict__ pbf,
                                                           const unsigned short* __restrict__ eperm,
                                                           const unsigned short* __restrict__ wfrag,
                                                           float* __restrict__ out) {
  __shared__ char smem[SMEM_BYTES];
  const int b = blockIdx.x & 7;    // batch <-> XCD (round-robin bid%8) for L2-resident staging
  const int pr = blockIdx.x >> 3;
  const int wave = threadIdx.x >> 6;
  const int lane = threadIdx.x & 63;
  const int qh = wave >> 1;   // q-half: rows [qh*16, qh*16+16) of the 32-row tile
  const int par = wave & 1;   // kv-parity: processes k-tiles 2i+par
  const int g = lane >> 4;
  const int l = lane & 15;
  const f32x4 zero = {0.f, 0.f, 0.f, 0.f};

  for (int ti = 0; ti < 2; ++ti) {
    const int t = ti ? (63 - pr) : pr;
    const int qbase = t * 32 + qh * 16;

    // Q frags in registers: qf[kc][i] = Q[lane&15][kc*32 + (lane>>4)*8 + i]  (q = p[:,1:,:])
    short8 qf[8];
    {
      const unsigned short* qrow = pbf + ((size_t)b * 2049 + qbase + l + 1) * 256;
#pragma unroll
      for (int kc = 0; kc < 8; ++kc) qf[kc] = *(const short8*)(qrow + kc * 32 + g * 8);
    }
    f32x4 yacc[16];
#pragma unroll
    for (int i = 0; i < 16; ++i) yacc[i] = zero;
    float dsum[4] = {0.f, 0.f, 0.f, 0.f};

    const int nkt = t + 1;            // causal: k-tiles 0..t
    const int iters = (nkt + 1) >> 1; // per-parity iterations

    if (par < nkt) stage_tiles(smem, 0, qh, par, par, b, lane, pbf, eperm);
    __syncthreads();

    for (int it = 0; it < iters; ++it) {
      const int cur = it & 1;
      // stage next tile FIRST (loads fly under this iteration's compute; barrier drains at end)
      const int ktn = 2 * (it + 1) + par;
      if (it + 1 < iters && ktn < nkt)
        stage_tiles(smem, cur ^ 1, qh, par, ktn, b, lane, pbf, eperm);

      const int kt = 2 * it + par;
      if (kt < nkt) {
        const char* kbuf = smem + cur * 65536 + par * 16384;
        const char* ebuf = kbuf + 32768;
        // QK^T: S[16q][32k], A=Q, B=K^T (b_frag[i]=K[n0*16+l][kc*32+g*8+i], XOR-swizzled read)
        f32x4 sacc[2];
        sacc[0] = zero;
        sacc[1] = zero;
#pragma unroll
        for (int kc = 0; kc < 8; ++kc) {
#pragma unroll
          for (int n0 = 0; n0 < 2; ++n0) {
            const int row = n0 * 16 + l;
            short8 bf =
                *(const short8*)(kbuf + row * 512 + ((kc * 64 + g * 16) ^ ((row & 7) << 4)));
            sacc[n0] = __builtin_amdgcn_mfma_f32_16x16x32_bf16(qf[kc], bf, sacc[n0], 0, 0, 0);
          }
        }
        // weights: w = exp(clip(s/16)), causal-masked; partials are additive (no max tracking)
        unsigned short* pp = (unsigned short*)(smem + 131072 + wave * 1280);
#pragma unroll
        for (int n0 = 0; n0 < 2; ++n0) {
          const int kg = kt * 32 + n0 * 16 + l;
#pragma unroll
          for (int j = 0; j < 4; ++j) {
            float s = sacc[n0][j] * 0.0625f;
            s = fminf(fmaxf(s, -10.f), 10.f);
            const int qg = qbase + g * 4 + j;
            float w = (kg <= qg) ? __expf(s) : 0.f;
            dsum[j] += w;
            pp[(g * 4 + j) * 40 + n0 * 16 + l] = f2b(w);  // P[16][40] padded
          }
        }
        // PV: A=P (via LDS round-trip), B=E fragment-linear; 16 independent acc chains
        short8 af = *(const short8*)((const unsigned short*)pp + l * 40 + g * 8);
#pragma unroll
        for (int d0 = 0; d0 < 16; ++d0) {
          short8 ef = *(const short8*)(ebuf + d0 * 1024 + lane * 16);
          yacc[d0] = __builtin_amdgcn_mfma_f32_16x16x32_bf16(af, ef, yacc[d0], 0, 0, 0);
        }
      }
      __syncthreads();
    }

    // full row-sums: reduce dsum across the 16 lanes (same lane>>4 group)
#pragma unroll
    for (int j = 0; j < 4; ++j) {
      float v = dsum[j];
      v += __shfl_xor(v, 1);
      v += __shfl_xor(v, 2);
      v += __shfl_xor(v, 4);
      v += __shfl_xor(v, 8);
      dsum[j] = v;
    }

    // combine kv-parity partials (par1 -> LDS, par0 adds + scales + writes PY bf16)
    float* yc = (float*)smem + qh * (16 * 257);
    float* dc = (float*)(smem + 136192) + qh * 16;
    if (par == 1) {
#pragma unroll
      for (int d0 = 0; d0 < 16; ++d0)
#pragma unroll
        for (int j = 0; j < 4; ++j) yc[(g * 4 + j) * 257 + d0 * 16 + l] = yacc[d0][j];
      if (l == 0) {
#pragma unroll
        for (int j = 0; j < 4; ++j) dc[g * 4 + j] = dsum[j];
      }
    }
    __syncthreads();
    unsigned short* py = (unsigned short*)(smem + 65536) + qh * (16 * 264);
    if (par == 0) {
      float inv[4];
#pragma unroll
      for (int j = 0; j < 4; ++j) {
        float dtot = dsum[j] + dc[g * 4 + j];
        const int qg = qbase + g * 4 + j;
        inv[j] = 1.f / (dtot * (float)(qg + 1));  // softmax denom * row_scale
      }
#pragma unroll
      for (int d0 = 0; d0 < 16; ++d0)
#pragma unroll
        for (int j = 0; j < 4; ++j)
          py[(g * 4 + j) * 264 + d0 * 16 + l] =
              f2b((yacc[d0][j] + yc[(g * 4 + j) * 257 + d0 * 16 + l]) * inv[j]);
    }
    __syncthreads();

    // epilogue: out[q][d] = sum_d' y[q][d'] * Wsum[d][d']; waves split d by parity
    {
      f32x4 oacc[8];
#pragma unroll
      for (int i = 0; i < 8; ++i) oacc[i] = zero;
#pragma unroll
      for (int kc = 0; kc < 8; ++kc) {
        short8 af2 = *(const short8*)(py + l * 264 + kc * 32 + g * 8);
#pragma unroll
        for (int dd = 0; dd < 8; ++dd) {
          const int d0 = par * 8 + dd;
          short8 wf = *(const short8*)(wfrag + ((size_t)(d0 * 8 + kc) * 64 + lane) * 8);
          oacc[dd] = __builtin_amdgcn_mfma_f32_16x16x32_bf16(af2, wf, oacc[dd], 0, 0, 0);
        }
      }
#pragma unroll
      for (int dd = 0; dd < 8; ++dd) {
#pragma unroll
        for (int j = 0; j < 4; ++j) {
          const int qg = qbase + g * 4 + j;
          const int d = (par * 8 + dd) * 16 + l;
          out[((size_t)b * 2048 + qg) * 256 + d] = oacc[dd][j];
        }
      }
    }
    __syncthreads();  // protect LDS before next tile's staging
  }
}

extern "C" void kernel_launch(void* const* d_in, const int* in_sizes, int n_in, void* d_out,
                              int out_size, void* d_ws, size_t ws_size, hipStream_t stream) {
  (void)in_sizes; (void)n_in; (void)out_size; (void)ws_size;
  const float* e = (const float*)d_in[0];    // [8][2048][256]
  const float* p = (const float*)d_in[1];    // [8][2049][256]
  const float* Wo = (const float*)d_in[2];   // [256][2048]
  float* out = (float*)d_out;                // [8][2048][256] f32

  unsigned short* pbf = (unsigned short*)d_ws;                        // 8,392,704 B
  unsigned short* eperm = (unsigned short*)((char*)d_ws + 8392704);   // 8,388,608 B
  unsigned short* wfrag = (unsigned short*)((char*)d_ws + 16781312);  // 131,072 B

  hipLaunchKernelGGL(cvt_p_kernel, dim3(2049), dim3(256), 0, stream, p, pbf);
  hipLaunchKernelGGL(perm_e_kernel, dim3(2048), dim3(256), 0, stream, e, eperm);
  hipLaunchKernelGGL(fold_w_kernel, dim3(32), dim3(256), 0, stream, Wo, wfrag);
  hipLaunchKernelGGL(attn_main_kernel, dim3(256), dim3(256), 0, stream, pbf, eperm, wfrag, out);
}